// Round 1
// baseline (963.343 us; speedup 1.0000x reference)
//
#include <hip/hip_runtime.h>
#include <math.h>

#define BS 256
#define HID 1024
#define ACT 16
#define MEM_DIM 512
#define NUM_MEM 1024
#define MEM_H 32

// ---- d_out layout (floats): read_v, other_v, M_new, alpha ----
#define OUT_READV 0
#define OUT_OTHER (BS * MEM_DIM)
#define OUT_MNEW  (2 * BS * MEM_DIM)
#define OUT_ALPHA (2 * BS * MEM_DIM + (size_t)BS * NUM_MEM * MEM_DIM)

// ---- ws layout (floats) ----
#define WS_ERASE 0
#define WS_ADD   (BS * MEM_DIM)
#define WS_G1    (2 * BS * MEM_DIM)
#define WS_K9    (3 * BS * MEM_DIM)   // BS*9 softmaxed conv kernels

typedef float v4f __attribute__((ext_vector_type(4)));

__device__ __forceinline__ float sigmoidf_(float x) { return 1.f / (1.f + expf(-x)); }
__device__ __forceinline__ float leakyf_(float x) { return x > 0.f ? x : 0.2f * x; }

// ---------------------------------------------------------------------------
// Kernel 1: per-batch kernel-net (orig + argmax-flip variant), softmax -> k9
// one wave (64 threads) per batch
// ---------------------------------------------------------------------------
__global__ __launch_bounds__(64) void knet_kernel(
    const float* __restrict__ a, const float* __restrict__ Wk1,
    const float* __restrict__ bk1, const float* __restrict__ Wk2,
    const float* __restrict__ bk2, float* __restrict__ k9out)
{
    int b = blockIdx.x;
    int t = threadIdx.x;
    __shared__ float as[ACT];
    if (t < ACT) as[t] = a[b * ACT + t];
    __syncthreads();

    // m = (argmax(a) == 0)  <=>  a[0] >= max(a[1..15])
    float mx = as[1];
    #pragma unroll
    for (int j = 2; j < ACT; ++j) mx = fmaxf(mx, as[j]);
    bool m = as[0] >= mx;

    float po[9], pn[9];
    #pragma unroll
    for (int o = 0; o < 9; ++o) { po[o] = 0.f; pn[o] = 0.f; }

    #pragma unroll
    for (int i = 0; i < 8; ++i) {
        int u = t + 64 * i;               // hidden unit (coalesced across lanes)
        float so = bk1[u], sn = bk1[u];
        #pragma unroll
        for (int j = 0; j < ACT; ++j) {
            float w  = Wk1[j * MEM_DIM + u];
            float av = as[j];
            float avn = (j == 0) ? (m ? 0.f : av)
                      : (j == 1) ? (m ? 1.f : av) : av;
            so += av * w;
            sn += avn * w;
        }
        so = leakyf_(so);
        sn = leakyf_(sn);
        #pragma unroll
        for (int o = 0; o < 9; ++o) {
            float w2 = Wk2[u * 9 + o];
            po[o] += so * w2;
            pn[o] += sn * w2;
        }
    }
    // wave-64 reduction of 9+9 partials
    #pragma unroll
    for (int off = 32; off; off >>= 1) {
        #pragma unroll
        for (int o = 0; o < 9; ++o) {
            po[o] += __shfl_down(po[o], off, 64);
            pn[o] += __shfl_down(pn[o], off, 64);
        }
    }
    if (t == 0) {
        float k[9];
        #pragma unroll
        for (int o = 0; o < 9; ++o) {
            float ko = po[o] + bk2[o];
            float kn = pn[8 - o] + bk2[8 - o];   // spatial flip of the new_a kernel
            k[o] = m ? kn : ko;
        }
        // softmax (ALPHA_T = 1)
        float kmax = k[0];
        #pragma unroll
        for (int o = 1; o < 9; ++o) kmax = fmaxf(kmax, k[o]);
        float s = 0.f;
        #pragma unroll
        for (int o = 0; o < 9; ++o) { k[o] = expf(k[o] - kmax); s += k[o]; }
        float inv = 1.f / s;
        #pragma unroll
        for (int o = 0; o < 9; ++o) k9out[b * 9 + o] = k[o] * inv;
    }
}

// ---------------------------------------------------------------------------
// Kernel 2: fused f32 GEMM  C = h(256x1024) @ [Wv(1024x1536) | Wg1(1024x512)]
// tile 32x64, Kc=32, 256 threads, each thread 2x4 accumulators.
// epilogue: seg0 sigmoid->ws_erase, seg1 raw->ws_add, seg2 raw->out_other,
//           seg3 leaky->ws_g1
// ---------------------------------------------------------------------------
#define TM 32
#define TN 64
#define KC 32

__global__ __launch_bounds__(256) void gemm_fused_kernel(
    const float* __restrict__ h, const float* __restrict__ Wv,
    const float* __restrict__ Wg1, const float* __restrict__ bv,
    const float* __restrict__ bg1, float* __restrict__ ws,
    float* __restrict__ out_other)
{
    __shared__ float As[KC][TM + 1];   // [k][m]
    __shared__ float Bs[KC][TN + 4];   // [k][n]
    int tid = threadIdx.x;
    int n0 = blockIdx.x * TN;          // 0..2047 (tile never straddles 512-seg)
    int m0 = blockIdx.y * TM;
    int tc = tid & 15, tr = tid >> 4;

    float acc[2][4];
    #pragma unroll
    for (int j = 0; j < 2; ++j)
        #pragma unroll
        for (int i = 0; i < 4; ++i) acc[j][i] = 0.f;

    int a_m  = tid >> 3;           // 0..31
    int a_k4 = (tid & 7) * 4;      // 0..28
    int b_n4 = (tid & 15) * 4;     // 0..60
    int b_k  = tid >> 4;           // 0..15
    const bool isWv = (n0 < 3 * MEM_DIM);

    for (int k0 = 0; k0 < HID; k0 += KC) {
        float4 av4 = *(const float4*)&h[(size_t)(m0 + a_m) * HID + k0 + a_k4];
        As[a_k4 + 0][a_m] = av4.x;
        As[a_k4 + 1][a_m] = av4.y;
        As[a_k4 + 2][a_m] = av4.z;
        As[a_k4 + 3][a_m] = av4.w;
        #pragma unroll
        for (int p = 0; p < 2; ++p) {
            int kk = b_k + p * 16;
            float4 bv4;
            if (isWv)
                bv4 = *(const float4*)&Wv[(size_t)(k0 + kk) * (3 * MEM_DIM) + n0 + b_n4];
            else
                bv4 = *(const float4*)&Wg1[(size_t)(k0 + kk) * MEM_DIM + (n0 - 3 * MEM_DIM) + b_n4];
            *(float4*)&Bs[kk][b_n4] = bv4;
        }
        __syncthreads();
        #pragma unroll
        for (int k = 0; k < KC; ++k) {
            float a0 = As[k][tr * 2 + 0];
            float a1 = As[k][tr * 2 + 1];
            float4 b4 = *(float4*)&Bs[k][tc * 4];
            acc[0][0] += a0 * b4.x; acc[0][1] += a0 * b4.y;
            acc[0][2] += a0 * b4.z; acc[0][3] += a0 * b4.w;
            acc[1][0] += a1 * b4.x; acc[1][1] += a1 * b4.y;
            acc[1][2] += a1 * b4.z; acc[1][3] += a1 * b4.w;
        }
        __syncthreads();
    }

    int seg = n0 >> 9;   // 0,1,2 -> Wv cols; 3 -> Wg1 cols
    #pragma unroll
    for (int j = 0; j < 2; ++j) {
        int r = m0 + tr * 2 + j;
        #pragma unroll
        for (int i = 0; i < 4; ++i) {
            int c = n0 + tc * 4 + i;
            float v = acc[j][i];
            if (seg < 3) v += bv[c]; else v += bg1[c - 3 * MEM_DIM];
            if (seg == 0)      ws[WS_ERASE + r * MEM_DIM + c]               = sigmoidf_(v);
            else if (seg == 1) ws[WS_ADD   + r * MEM_DIM + (c - MEM_DIM)]   = v;
            else if (seg == 2) out_other[r * MEM_DIM + (c - 2 * MEM_DIM)]   = v;
            else               ws[WS_G1    + r * MEM_DIM + (c - 3 * MEM_DIM)] = leakyf_(v);
        }
    }
}

// ---------------------------------------------------------------------------
// Kernel 3: per-batch gate (g1 . Wg2 -> sigmoid) + 3x3 SAME cross-correlation
// conv of prev_alpha (32x32), gate blend -> alpha
// ---------------------------------------------------------------------------
__global__ __launch_bounds__(256) void conv_gate_kernel(
    const float* __restrict__ prev_alpha, const float* __restrict__ g1,
    const float* __restrict__ Wg2, const float* __restrict__ bg2,
    const float* __restrict__ k9, float* __restrict__ alpha_out)
{
    int b = blockIdx.x;
    int t = threadIdx.x;
    __shared__ float pa[NUM_MEM];
    __shared__ float ksh[9];
    __shared__ float red[4];
    __shared__ float gsh;

    // gate partial: 512 values, 2 per thread
    float p = g1[b * MEM_DIM + t] * Wg2[t]
            + g1[b * MEM_DIM + 256 + t] * Wg2[256 + t];
    #pragma unroll
    for (int off = 32; off; off >>= 1) p += __shfl_down(p, off, 64);
    if ((t & 63) == 0) red[t >> 6] = p;

    *(float4*)&pa[t * 4] = *(const float4*)&prev_alpha[b * NUM_MEM + t * 4];
    if (t < 9) ksh[t] = k9[b * 9 + t];
    __syncthreads();
    if (t == 0) gsh = sigmoidf_(red[0] + red[1] + red[2] + red[3] + bg2[0]);
    __syncthreads();
    float gate = gsh;

    #pragma unroll
    for (int q = 0; q < 4; ++q) {
        int c = t * 4 + q;
        int i = c >> 5, j = c & 31;
        float s = 0.f;
        #pragma unroll
        for (int ki = 0; ki < 3; ++ki) {
            int ii = i + ki - 1;
            if (ii < 0 || ii >= MEM_H) continue;
            #pragma unroll
            for (int kj = 0; kj < 3; ++kj) {
                int jj = j + kj - 1;
                if (jj < 0 || jj >= MEM_H) continue;
                s += pa[ii * MEM_H + jj] * ksh[ki * 3 + kj];
            }
        }
        alpha_out[b * NUM_MEM + c] = s * gate + pa[c] * (1.f - gate);
    }
}

// ---------------------------------------------------------------------------
// Kernel 4: the streaming update.  M_new = M*(1-alpha*erase) + alpha*add,
// read_v += alpha * M_new  (atomic partial per n-chunk).
// grid (b=256, nchunk=4), 256 threads; thread -> (n parity, 4 d's)
// ---------------------------------------------------------------------------
__global__ __launch_bounds__(256) void update_kernel(
    const float* __restrict__ M, const float* __restrict__ alpha,
    const float* __restrict__ erase, const float* __restrict__ add,
    float* __restrict__ M_new, float* __restrict__ read_v)
{
    int b  = blockIdx.x;
    int nc = blockIdx.y;
    int t  = threadIdx.x;
    int n_off = t >> 7;         // wave-uniform (0 for waves 0-1, 1 for 2-3)
    int d = (t & 127) * 4;

    __shared__ float al[256];
    al[t] = alpha[b * NUM_MEM + nc * 256 + t];
    __syncthreads();

    v4f e  = *(const v4f*)(erase + b * MEM_DIM + d);
    v4f ad = *(const v4f*)(add   + b * MEM_DIM + d);
    const float* Mb = M     + (size_t)b * NUM_MEM * MEM_DIM + (size_t)(nc * 256) * MEM_DIM + d;
    float*       Ob = M_new + (size_t)b * NUM_MEM * MEM_DIM + (size_t)(nc * 256) * MEM_DIM + d;

    v4f acc = 0.f;
    #pragma unroll 8
    for (int ni = n_off; ni < 256; ni += 2) {
        float av = al[ni];
        v4f m4 = __builtin_nontemporal_load((const v4f*)(Mb + (size_t)ni * MEM_DIM));
        v4f mn = m4 * (1.f - av * e) + av * ad;
        __builtin_nontemporal_store(mn, (v4f*)(Ob + (size_t)ni * MEM_DIM));
        acc += av * mn;
    }
    float* rv = read_v + b * MEM_DIM + d;
    atomicAdd(rv + 0, acc.x);
    atomicAdd(rv + 1, acc.y);
    atomicAdd(rv + 2, acc.z);
    atomicAdd(rv + 3, acc.w);
}

// ---------------------------------------------------------------------------
extern "C" void kernel_launch(void* const* d_in, const int* in_sizes, int n_in,
                              void* d_out, int out_size, void* d_ws, size_t ws_size,
                              hipStream_t stream)
{
    const float* h          = (const float*)d_in[0];
    const float* a          = (const float*)d_in[1];
    // d_in[2] = prev_h (unused by the reference)
    const float* prev_alpha = (const float*)d_in[3];
    const float* M          = (const float*)d_in[4];
    const float* Wv         = (const float*)d_in[5];
    const float* bv         = (const float*)d_in[6];
    const float* Wk1        = (const float*)d_in[7];
    const float* bk1        = (const float*)d_in[8];
    const float* Wk2        = (const float*)d_in[9];
    const float* bk2        = (const float*)d_in[10];
    const float* Wg1        = (const float*)d_in[11];
    const float* bg1        = (const float*)d_in[12];
    const float* Wg2        = (const float*)d_in[13];
    const float* bg2        = (const float*)d_in[14];

    float* out = (float*)d_out;
    float* ws  = (float*)d_ws;

    float* out_readv = out + OUT_READV;
    float* out_other = out + OUT_OTHER;
    float* out_mnew  = out + OUT_MNEW;
    float* out_alpha = out + OUT_ALPHA;

    // read_v is accumulated atomically -> must start at zero every call
    hipMemsetAsync(out_readv, 0, (size_t)BS * MEM_DIM * sizeof(float), stream);

    knet_kernel<<<BS, 64, 0, stream>>>(a, Wk1, bk1, Wk2, bk2, ws + WS_K9);
    gemm_fused_kernel<<<dim3(2048 / TN, BS / TM), 256, 0, stream>>>(
        h, Wv, Wg1, bv, bg1, ws, out_other);
    conv_gate_kernel<<<BS, 256, 0, stream>>>(
        prev_alpha, ws + WS_G1, Wg2, bg2, ws + WS_K9, out_alpha);
    update_kernel<<<dim3(BS, 4), 256, 0, stream>>>(
        M, out_alpha, ws + WS_ERASE, ws + WS_ADD, out_mnew, out_readv);
}